// Round 14
// baseline (394.693 us; speedup 1.0000x reference)
//
#include <hip/hip_runtime.h>
#include <math.h>

#define B_CUR 4096
#define N_TOT 8192
#define C_F   256
#define C_TOT 288
#define KSEL  16
#define NTILE 64    // 8192 / 128

typedef unsigned short u16;
typedef __attribute__((ext_vector_type(8))) short short8;
typedef __attribute__((ext_vector_type(4))) float floatx4;

__device__ inline float bf2f(u16 v) {
  union { unsigned int u; float f; } x; x.u = ((unsigned int)v) << 16; return x.f;
}
__device__ inline u16 f2bf(float f) {
  union { float f; unsigned int u; } x; x.f = f;
  unsigned int u = x.u;
  u += ((u >> 16) & 1u) + 0x7FFFu;   // RNE
  return (u16)(u >> 16);
}

#define GLD_LDS16(g, l) __builtin_amdgcn_global_load_lds(                      \
    (const __attribute__((address_space(1))) unsigned int*)(g),                \
    (__attribute__((address_space(3))) unsigned int*)(l), 16, 0, 0)

// K1 (fused): per wave = one row. Feature normalize (64 lanes) + PE (32 lanes).
__global__ __launch_bounds__(256) void k_prep(
    const float* __restrict__ feats, const float* __restrict__ hfeats,
    const float* __restrict__ coords, const float* __restrict__ hcoords,
    u16* __restrict__ Zb, float* __restrict__ out_nf) {
  int wave = threadIdx.x >> 6;
  int lane = threadIdx.x & 63;
  int row  = blockIdx.x * 4 + wave;
  const float* src = (row < B_CUR) ? (feats + (size_t)row * C_F)
                                   : (hfeats + (size_t)(row - B_CUR) * C_F);
  int c0 = lane * 4;
  float4 raw = *(const float4*)(src + c0);
  float ss = raw.x*raw.x + raw.y*raw.y + raw.z*raw.z + raw.w*raw.w;
  #pragma unroll
  for (int m = 32; m; m >>= 1) ss += __shfl_xor(ss, m, 64);
  float scale = 0.97467943448089633f / fmaxf(sqrtf(ss), 1e-12f);   // sqrt(0.95)
  ushort4 o;
  o.x = f2bf(raw.x*scale); o.y = f2bf(raw.y*scale);
  o.z = f2bf(raw.z*scale); o.w = f2bf(raw.w*scale);
  *(ushort4*)(Zb + (size_t)row * C_TOT + c0) = o;
  *(float4*)(out_nf + (size_t)row * C_F + c0) = raw;

  const float* csrc = (row < B_CUR) ? (coords + (size_t)row * 4)
                                    : (hcoords + (size_t)(row - B_CUR) * 4);
  int d = lane >> 3, sc = (lane >> 2) & 1, f = lane & 3;
  float c = csrc[d & 3];
  float ang = c * 6.283185307179586f * (float)(1 << f);
  float pe = sc ? cosf(ang) : sinf(ang);
  float p2 = pe * pe;
  #pragma unroll
  for (int m = 16; m; m >>= 1) p2 += __shfl_xor(p2, m, 64);
  float pscale = 0.22360679774997896f / fmaxf(sqrtf(p2), 1e-12f); // sqrt(0.05)
  if (lane < 32) Zb[(size_t)row * C_TOT + C_F + lane] = f2bf(pe * pscale);
}

// K3: S = Zb Zb^T, symmetric (upper-triangle tiles, mirrored epilogue).
//     BK=32 double-buffered global_load_lds staging; S16 (bf16, dense 16KB rows)
//     written to workspace, not d_out.
#define EP_STRIDE 136
__global__ __launch_bounds__(256) void k_gemm_mfma(const u16* __restrict__ Zb,
                                                   u16* __restrict__ s16) {
  // union: staging (4 x 128x32 u16 = 16384) | epilogue (128 x 136 = 17408)
  __shared__ __align__(16) u16 smem[17408];            // 34816 B
  int tid  = threadIdx.x;

  int t = blockIdx.x;
  int bi = (int)floorf(((2.0f*NTILE + 1.0f) -
            sqrtf((float)((2*NTILE+1)*(2*NTILE+1)) - 8.0f*(float)t)) * 0.5f);
  if (bi < 0) bi = 0; if (bi > NTILE-1) bi = NTILE-1;
  while (bi > 0 && t < bi*NTILE - bi*(bi-1)/2) --bi;
  while (bi < NTILE-1 && t >= (bi+1)*NTILE - (bi+1)*bi/2) ++bi;
  int bj = bi + (t - (bi*NTILE - bi*(bi-1)/2));

  int wave = tid >> 6, lane = tid & 63;
  int quad = lane >> 4, l16 = lane & 15;
  int m0w  = (wave >> 1) * 64;
  int n0w  = (wave & 1) * 64;
  int i0   = bi * 128, j0 = bj * 128;

  // staging layout: A0 @0, B0 @4096, A1 @8192, B1 @12288 (u16 offsets)
  int srow0 = tid >> 2;            // seg s=tid   -> row
  int scol0 = (tid & 3) * 8;       //             -> u16 col

  floatx4 acc[4][4];
  #pragma unroll
  for (int a = 0; a < 4; ++a)
    #pragma unroll
    for (int b = 0; b < 4; ++b) acc[a][b] = (floatx4){0.f, 0.f, 0.f, 0.f};

  // prologue: stage chunk 0 into buffer 0
  {
    const u16* ga0 = Zb + (size_t)(i0 + srow0) * C_TOT + scol0;
    const u16* gb0 = Zb + (size_t)(j0 + srow0) * C_TOT + scol0;
    const u16* ga1 = Zb + (size_t)(i0 + srow0 + 64) * C_TOT + scol0;
    const u16* gb1 = Zb + (size_t)(j0 + srow0 + 64) * C_TOT + scol0;
    GLD_LDS16(ga0, smem + 0    + tid * 8);
    GLD_LDS16(ga1, smem + 0    + (tid + 256) * 8);
    GLD_LDS16(gb0, smem + 4096 + tid * 8);
    GLD_LDS16(gb1, smem + 4096 + (tid + 256) * 8);
  }
  __builtin_amdgcn_s_waitcnt(0);
  __syncthreads();

  for (int i = 0; i < 9; ++i) {
    int p = i & 1;
    if (i < 8) {
      int kt = (i + 1) * 32;
      u16* dstA = smem + (p ^ 1) * 8192;
      u16* dstB = dstA + 4096;
      const u16* ga0 = Zb + (size_t)(i0 + srow0) * C_TOT + kt + scol0;
      const u16* gb0 = Zb + (size_t)(j0 + srow0) * C_TOT + kt + scol0;
      const u16* ga1 = Zb + (size_t)(i0 + srow0 + 64) * C_TOT + kt + scol0;
      const u16* gb1 = Zb + (size_t)(j0 + srow0 + 64) * C_TOT + kt + scol0;
      GLD_LDS16(ga0, dstA + tid * 8);
      GLD_LDS16(ga1, dstA + (tid + 256) * 8);
      GLD_LDS16(gb0, dstB + tid * 8);
      GLD_LDS16(gb1, dstB + (tid + 256) * 8);
    }
    const u16* As = smem + p * 8192;
    const u16* Bs = As + 4096;
    short8 af[4], bf[4];
    #pragma unroll
    for (int mi = 0; mi < 4; ++mi)
      af[mi] = *(const short8*)(&As[(m0w + mi*16 + l16) * 32 + quad * 8]);
    #pragma unroll
    for (int ni = 0; ni < 4; ++ni)
      bf[ni] = *(const short8*)(&Bs[(n0w + ni*16 + l16) * 32 + quad * 8]);
    #pragma unroll
    for (int mi = 0; mi < 4; ++mi)
      #pragma unroll
      for (int ni = 0; ni < 4; ++ni)
        acc[mi][ni] = __builtin_amdgcn_mfma_f32_16x16x32_bf16(
            af[mi], bf[ni], acc[mi][ni], 0, 0, 0);
    __builtin_amdgcn_s_waitcnt(0);   // drain next-buffer loads (overlapped w/ MFMA)
    __syncthreads();
  }

  float w = ((bi < 32) != (bj < 32)) ? 0.5f : 1.0f;

  // pass 1: normal orientation -> tile (bi, bj) in dense S16 rows (16KB/row)
  #pragma unroll
  for (int mi = 0; mi < 4; ++mi) {
    #pragma unroll
    for (int ni = 0; ni < 4; ++ni) {
      int col = n0w + ni * 16 + l16;
      #pragma unroll
      for (int rg = 0; rg < 4; ++rg) {
        int row = m0w + mi * 16 + quad * 4 + rg;
        smem[row * EP_STRIDE + col] = f2bf(acc[mi][ni][rg] * w);
      }
    }
  }
  __syncthreads();
  #pragma unroll
  for (int it = 0; it < 8; ++it) {
    int idx = it * 256 + tid;
    int row = idx >> 4, l = idx & 15;
    uint4 v = *(const uint4*)(&smem[row * EP_STRIDE + l * 8]);
    *(uint4*)(&s16[(size_t)(i0 + row) * N_TOT + j0 + l * 8]) = v;
  }

  if (bi != bj) {
    __syncthreads();
    #pragma unroll
    for (int mi = 0; mi < 4; ++mi) {
      #pragma unroll
      for (int ni = 0; ni < 4; ++ni) {
        int col = n0w + ni * 16 + l16;
        #pragma unroll
        for (int rg = 0; rg < 4; ++rg) {
          int row = m0w + mi * 16 + quad * 4 + rg;
          smem[col * EP_STRIDE + row] = f2bf(acc[mi][ni][rg] * w);
        }
      }
    }
    __syncthreads();
    #pragma unroll
    for (int it = 0; it < 8; ++it) {
      int idx = it * 256 + tid;
      int row = idx >> 4, l = idx & 15;
      uint4 v = *(const uint4*)(&smem[row * EP_STRIDE + l * 8]);
      *(uint4*)(&s16[(size_t)(j0 + row) * N_TOT + i0 + l * 8]) = v;
    }
  }
}

// K4: per-row top-16, register-resident. S16 lives in ws (disjoint from d_out),
//     so reads and the non-temporal zero-fill of the f32 row proceed barrier-free.
__global__ __launch_bounds__(256) void k_topk(
    const u16* __restrict__ s16, float* __restrict__ adj,
    int* __restrict__ topk_idx, float* __restrict__ topk_val,
    float* __restrict__ deg_out) {
  __shared__ unsigned int cand[64];
  __shared__ float s_diag;
  int r = blockIdx.x;
  int t = threadIdx.x;
  int wave = t >> 6, lane = t & 63;
  const u16* rowp = s16 + (size_t)r * N_TOT;

  // issue row reads (registers) ...
  uint4 raw[4];
  #pragma unroll
  for (int j = 0; j < 4; ++j)
    raw[j] = *(const uint4*)(rowp + j * 2048 + t * 8);
  if (t == 0) s_diag = bf2f(rowp[r]);   // consumed after the merge barrier

  // ... and the zero-fill concurrently (disjoint memory, non-temporal).
  {
    float* oro = adj + (size_t)r * N_TOT;
    const floatx4 z4 = (floatx4){0.f, 0.f, 0.f, 0.f};
    #pragma unroll
    for (int kk = 0; kk < 8; ++kk)
      __builtin_nontemporal_store(z4, (floatx4*)(oro + kk * 1024 + t * 4));
  }

  // build packed keys: high16 = sortable bf16, low13 = 8191-col
  unsigned int keys[32];
  #pragma unroll
  for (int j = 0; j < 4; ++j) {
    int c0 = j * 2048 + t * 8;
    u16 e[8]; *(uint4*)e = raw[j];
    #pragma unroll
    for (int q = 0; q < 8; ++q) {
      int col = c0 + q;
      unsigned int b = e[q];
      unsigned int s16v = (b & 0x8000u) ? (b ^ 0xFFFFu) : (b | 0x8000u);
      unsigned int k = (s16v << 16) | (unsigned int)(8191 - col);
      if (col == r) k = 0xFFFF0000u | (unsigned int)(8191 - r);  // forced max
      keys[j * 8 + q] = k;
    }
  }

  // per-thread top-2 (with slot indices)
  unsigned int m1 = 0, m2 = 0; int i1 = 0, i2 = 0;
  #pragma unroll
  for (int i = 0; i < 32; ++i) {
    unsigned int k = keys[i];
    if (k > m1) { m2 = m1; i2 = i1; m1 = k; i1 = i; }
    else if (k > m2) { m2 = k; i2 = i; }
  }
  unsigned int taken = 0;

  // wave-local top-16, zero barriers
  for (int it = 0; it < KSEL; ++it) {
    unsigned int wmax = m1;
    #pragma unroll
    for (int s = 32; s; s >>= 1) {
      unsigned int o = (unsigned int)__shfl_xor((int)wmax, s, 64);
      wmax = (o > wmax) ? o : wmax;
    }
    if (lane == it) cand[wave * 16 + it] = wmax;
    if (m1 == wmax && m1 != 0) {
      taken |= 1u << i1;
      if (m2 != 0) { m1 = m2; i1 = i2; m2 = 0; }
      else {
        m1 = 0; m2 = 0; i1 = 0; i2 = 0;
        #pragma unroll
        for (int i = 0; i < 32; ++i) {
          unsigned int k = (taken & (1u << i)) ? 0u : keys[i];
          if (k > m1) { m2 = m1; i2 = i1; m1 = k; i1 = i; }
          else if (k > m2) { m2 = k; i2 = i; }
        }
      }
    }
  }
  __syncthreads();

  // wave 0 merges 64 candidates -> global top-16
  if (wave == 0) {
    unsigned int c = cand[lane];
    unsigned int myWin = 0;
    for (int it = 0; it < KSEL; ++it) {
      unsigned int wmax = c;
      #pragma unroll
      for (int s = 32; s; s >>= 1) {
        unsigned int o = (unsigned int)__shfl_xor((int)wmax, s, 64);
        wmax = (o > wmax) ? o : wmax;
      }
      if (c == wmax) c = 0;
      if (lane == it) myWin = wmax;
    }
    float val = 0.f;
    int col = 0;
    if (lane < KSEL) {
      unsigned int p = myWin;
      col = 8191 - (int)(p & 0x1FFFu);
      unsigned int k16 = p >> 16;
      unsigned int b = (k16 & 0x8000u) ? (k16 ^ 0x8000u) : ((~k16) & 0xFFFFu);
      val = (col == r) ? s_diag : bf2f((u16)b);
      topk_idx[r * KSEL + lane] = col;
      topk_val[r * KSEL + lane] = val;
    }
    float s = (lane < KSEL) ? val : 0.f;
    #pragma unroll
    for (int m = 8; m; m >>= 1) s += __shfl_xor(s, m, 64);
    if (lane == 0) deg_out[r] = s;
  }
}

// K5: scatter the 16 scaled entries per row (zeros already written by k_topk).
__global__ void k_scale(float* __restrict__ adj, const int* __restrict__ topk_idx,
                        const float* __restrict__ topk_val,
                        const float* __restrict__ deg) {
  int g = blockIdx.x * blockDim.x + threadIdx.x;
  if (g >= N_TOT * KSEL) return;
  int r = g >> 4, m = g & 15;
  int j = topk_idx[r * KSEL + m];
  if (j < 0) j = 0; if (j >= N_TOT) j = N_TOT - 1;   // insurance
  float v = topk_val[r * KSEL + m];
  float di = 1.0f / sqrtf(fmaxf(deg[r], 1e-12f));
  float dj = 1.0f / sqrtf(fmaxf(deg[j], 1e-12f));
  adj[(size_t)r * N_TOT + j] = v * di * dj;
}

extern "C" void kernel_launch(void* const* d_in, const int* in_sizes, int n_in,
                              void* d_out, int out_size, void* d_ws, size_t ws_size,
                              hipStream_t stream) {
  const float* feats   = (const float*)d_in[0];
  const float* coords  = (const float*)d_in[1];
  const float* hfeats  = (const float*)d_in[2];
  const float* hcoords = (const float*)d_in[3];
  float* out    = (float*)d_out;
  float* adj    = out;                               // [8192, 8192] f32
  float* out_nf = out + (size_t)N_TOT * N_TOT;       // [8192, 256]  f32

  char* ws    = (char*)d_ws;
  u16*  Zb    = (u16*)ws;                            // 4.7 MB
  size_t zb   = (size_t)N_TOT * C_TOT * sizeof(u16);
  zb = (zb + 255) & ~(size_t)255;
  int*   t_idx = (int*)(ws + zb);
  float* t_val = (float*)(ws + zb + (size_t)N_TOT*KSEL*sizeof(int));
  float* deg   = (float*)(ws + zb + (size_t)N_TOT*KSEL*(sizeof(int)+sizeof(float)));
  u16*   s16   = (u16*)(ws + (16u << 20));           // 134 MB bf16 S at +16 MiB

  hipLaunchKernelGGL(k_prep, dim3(N_TOT/4), dim3(256), 0, stream,
                     feats, hfeats, coords, hcoords, Zb, out_nf);
  hipLaunchKernelGGL(k_gemm_mfma, dim3(NTILE*(NTILE+1)/2), dim3(256), 0, stream,
                     Zb, s16);
  hipLaunchKernelGGL(k_topk, dim3(N_TOT), dim3(256), 0, stream,
                     s16, adj, t_idx, t_val, deg);
  hipLaunchKernelGGL(k_scale, dim3((N_TOT*KSEL + 255)/256), dim3(256), 0, stream,
                     adj, t_idx, t_val, deg);
}